// Round 1
// baseline (7994.732 us; speedup 1.0000x reference)
//
#include <hip/hip_runtime.h>
#include <hip/hip_bf16.h>

#define B_ 128
#define T_ 200
#define H_ 512
#define G_ 2048   // 4*H
#define E_ 300

typedef unsigned short u16;
typedef unsigned int u32;

using f32x4 = __attribute__((ext_vector_type(4))) float;
using s16x8 = __attribute__((ext_vector_type(8))) short;

__device__ __forceinline__ u16 f2bf(float f) {
  u32 u = __builtin_bit_cast(u32, f);
  u32 r = (u + 0x7fffu + ((u >> 16) & 1u)) >> 16;   // RNE
  return (u16)r;
}
__device__ __forceinline__ float bf2f(u16 s) {
  return __builtin_bit_cast(float, (u32)s << 16);
}

// ---------------------------------------------------------------------------
// xg = emb[tok] @ Wih^T + bih + bhh   (M=25600, N=2048, K=300 pad 320), bf16 out
// grid (400, 64), block 256. Tile 64(M) x 32(N). LDS: A 40KB + B 20KB, swizzled.
// ---------------------------------------------------------------------------
__global__ __launch_bounds__(256) void xg_gemm(
    const int* __restrict__ tok, const float* __restrict__ emb,
    const float* __restrict__ Wih, const float* __restrict__ bih,
    const float* __restrict__ bhh, u16* __restrict__ xg)
{
  __shared__ u16 Al[64 * 320];
  __shared__ u16 Bl[32 * 320];
  __shared__ int tks[64];
  const int tid = threadIdx.x;
  const int m0 = blockIdx.x * 64;
  const int n0 = blockIdx.y * 32;
  if (tid < 64) tks[tid] = tok[m0 + tid];
  __syncthreads();
  {
    // A-tile: 64 rows x 160 u32-words (bf16x2), k padded 300->320 with zeros
    const int row = tid >> 2, part = tid & 3;
    const float* erow = emb + (size_t)tks[row] * E_;
    char* base = (char*)Al + row * 640;
    const int swz = (row & 7) << 4;
#pragma unroll
    for (int i = 0; i < 40; ++i) {
      const int kw = part * 40 + i;
      const int k = kw * 2;
      const float v0 = (k < E_) ? erow[k] : 0.f;
      const float v1 = (k + 1 < E_) ? erow[k + 1] : 0.f;
      *(u32*)(base + ((kw * 4) ^ swz)) = (u32)f2bf(v0) | ((u32)f2bf(v1) << 16);
    }
    // B-tile: 32 rows (gates) x 160 words
    const int brow = tid >> 3, bpart = tid & 7;
    const float* wrow = Wih + (size_t)(n0 + brow) * E_;
    char* bbase = (char*)Bl + brow * 640;
    const int bswz = (brow & 7) << 4;
#pragma unroll
    for (int i = 0; i < 20; ++i) {
      const int kw = bpart * 20 + i;
      const int k = kw * 2;
      const float v0 = (k < E_) ? wrow[k] : 0.f;
      const float v1 = (k + 1 < E_) ? wrow[k + 1] : 0.f;
      *(u32*)(bbase + ((kw * 4) ^ bswz)) = (u32)f2bf(v0) | ((u32)f2bf(v1) << 16);
    }
  }
  __syncthreads();
  const int wv = tid >> 6, ln = tid & 63, lr = ln & 15, lq = ln >> 4;
  f32x4 acc0 = {0.f, 0.f, 0.f, 0.f}, acc1 = {0.f, 0.f, 0.f, 0.f};
  const int arow = wv * 16 + lr;                 // wave wv owns M-tile wv
  const char* abase = (const char*)Al + arow * 640;
  const int aswz = (arow & 7) << 4;
  const char* b0base = (const char*)Bl + lr * 640;
  const char* b1base = (const char*)Bl + (16 + lr) * 640;
  const int bswz2 = (lr & 7) << 4;
#pragma unroll
  for (int ks = 0; ks < 10; ++ks) {
    const int kb = ks * 64 + lq * 16;            // byte offset along K
    s16x8 af  = *(const s16x8*)(abase  + (kb ^ aswz));
    s16x8 bf0 = *(const s16x8*)(b0base + (kb ^ bswz2));
    s16x8 bf1 = *(const s16x8*)(b1base + (kb ^ bswz2));
    acc0 = __builtin_amdgcn_mfma_f32_16x16x32_bf16(af, bf0, acc0, 0, 0, 0);
    acc1 = __builtin_amdgcn_mfma_f32_16x16x32_bf16(af, bf1, acc1, 0, 0, 0);
  }
#pragma unroll
  for (int r = 0; r < 4; ++r) {
    const int m = m0 + wv * 16 + lq * 4 + r;     // C/D: row=(lane>>4)*4+reg, col=lane&15
    const int gA = n0 + lr;
    const int gB = n0 + 16 + lr;
    xg[(size_t)m * G_ + gA] = f2bf(acc0[r] + bih[gA] + bhh[gA]);
    xg[(size_t)m * G_ + gB] = f2bf(acc1[r] + bih[gB] + bhh[gB]);
  }
}

// ---------------------------------------------------------------------------
// Persistent LSTM recurrence. 32 WGs x 256 thr. WG jt owns j-slice [jt*16,+16)
// and gate rows {q*512 + j} q=0..3 (64 rows of Whh, staged bf16+swizzled in LDS
// once). c and the mask-blend state live in VGPRs for all 200 steps. h is
// exchanged via a double-buffered global bf16 buffer + device-scope barrier.
// TRACK_C=1: premise (tracks masked c, writes cOut). 0: hypothesis (tracks
// masked h, reads c0in, writes mhOut).
// ---------------------------------------------------------------------------
template<int TRACK_C>
__global__ __launch_bounds__(256) void lstm_rec(
    const int* __restrict__ tok, const u16* __restrict__ xg,
    const float* __restrict__ Whh, u16* __restrict__ hbuf,
    const float* __restrict__ c0in, float* __restrict__ cOut,
    float* __restrict__ mhOut, int* __restrict__ counter)
{
  __shared__ u16 Wl[64 * 512];   // 64 KB
  const int tid = threadIdx.x;
  const int jt = blockIdx.x;
  const int j0 = jt * 16;
  {
    // preload Whh slice -> bf16 LDS (row n = q*16+jj <-> Whh row q*512+j0+jj)
    const int row = tid >> 2, part = tid & 3;
    const int q = row >> 4, jj = row & 15;
    const float* wr = Whh + (size_t)(q * 512 + j0 + jj) * H_;
    char* base = (char*)Wl + row * 1024;
    const int swz = (row & 7) << 4;
#pragma unroll
    for (int i = 0; i < 64; ++i) {
      const int kw = part * 64 + i;
      const int k = kw * 2;
      *(u32*)(base + ((kw * 4) ^ swz)) = (u32)f2bf(wr[k]) | ((u32)f2bf(wr[k + 1]) << 16);
    }
  }
  // zero our j-slice of h ping buffer 0 (h0 = 0)
  for (int i = tid; i < B_ * 16; i += 256) {
    const int b = i >> 4, jj = i & 15;
    hbuf[b * H_ + j0 + jj] = 0;
  }
  const int wv = tid >> 6, ln = tid & 63, lr = ln & 15, lq = ln >> 4;
  float c[2][4], mblend[2][4];
#pragma unroll
  for (int a = 0; a < 2; ++a)
#pragma unroll
    for (int r = 0; r < 4; ++r) {
      const int b = (2 * wv + a) * 16 + lq * 4 + r;
      float cv = 0.f;
      if (!TRACK_C) cv = c0in[b * H_ + j0 + lr];
      c[a][r] = cv;
      mblend[a][r] = TRACK_C ? cv : 0.f;  // blend carry init = (h0=0, c0)
    }
  __threadfence();
  __syncthreads();
  if (tid == 0) {
    __hip_atomic_fetch_add(counter, 1, __ATOMIC_RELEASE, __HIP_MEMORY_SCOPE_AGENT);
    while (__hip_atomic_load(counter, __ATOMIC_RELAXED, __HIP_MEMORY_SCOPE_AGENT) < 32)
      __builtin_amdgcn_s_sleep(2);
    (void)__hip_atomic_load(counter, __ATOMIC_ACQUIRE, __HIP_MEMORY_SCOPE_AGENT);
  }
  __syncthreads();

  const int bswz = (lr & 7) << 4;
  for (int t = 0; t < T_; ++t) {
    const u16* __restrict__ hrd = hbuf + (t & 1) * (B_ * H_);
    u16* __restrict__ hwr = hbuf + ((t + 1) & 1) * (B_ * H_);
    f32x4 acc[2][4];
#pragma unroll
    for (int a = 0; a < 2; ++a)
#pragma unroll
      for (int q = 0; q < 4; ++q) acc[a][q] = (f32x4){0.f, 0.f, 0.f, 0.f};
#pragma unroll 4
    for (int ks = 0; ks < 16; ++ks) {
      const int kb = ks * 64 + lq * 16;
      // A-frags straight from global h (row = lane&15, 8 contiguous k) — reused over 4 gates
      s16x8 a0 = *(const s16x8*)((const char*)hrd + ((2 * wv + 0) * 16 + lr) * 1024 + kb);
      s16x8 a1 = *(const s16x8*)((const char*)hrd + ((2 * wv + 1) * 16 + lr) * 1024 + kb);
#pragma unroll
      for (int q = 0; q < 4; ++q) {
        s16x8 bfr = *(const s16x8*)((const char*)Wl + (q * 16 + lr) * 1024 + (kb ^ bswz));
        acc[0][q] = __builtin_amdgcn_mfma_f32_16x16x32_bf16(a0, bfr, acc[0][q], 0, 0, 0);
        acc[1][q] = __builtin_amdgcn_mfma_f32_16x16x32_bf16(a1, bfr, acc[1][q], 0, 0, 0);
      }
    }
    const bool last = (t == T_ - 1);
#pragma unroll
    for (int a = 0; a < 2; ++a)
#pragma unroll
      for (int r = 0; r < 4; ++r) {
        const int b = (2 * wv + a) * 16 + lq * 4 + r;
        const size_t xo = ((size_t)b * T_ + t) * G_ + j0 + lr;
        const float gi = acc[a][0][r] + bf2f(xg[xo]);
        const float gf = acc[a][1][r] + bf2f(xg[xo + 512]);
        const float gg = acc[a][2][r] + bf2f(xg[xo + 1024]);
        const float go = acc[a][3][r] + bf2f(xg[xo + 1536]);
        const float si = 1.f / (1.f + __expf(-gi));
        const float sf = 1.f / (1.f + __expf(-gf));
        const float so = 1.f / (1.f + __expf(-go));
        const float tg = 2.f / (1.f + __expf(-2.f * gg)) - 1.f;
        const float cn = sf * c[a][r] + si * tg;
        const float tc = 2.f / (1.f + __expf(-2.f * cn)) - 1.f;
        const float hn = so * tc;
        c[a][r] = cn;
        const bool mk = (tok[b * T_ + t] != 0);
        if (mk) mblend[a][r] = TRACK_C ? cn : hn;
        if (!last) hwr[b * H_ + j0 + lr] = f2bf(hn);
      }
    if (!last) {
      __threadfence();
      __syncthreads();
      if (tid == 0) {
        __hip_atomic_fetch_add(counter, 1, __ATOMIC_RELEASE, __HIP_MEMORY_SCOPE_AGENT);
        const int target = 32 * (t + 2);
        while (__hip_atomic_load(counter, __ATOMIC_RELAXED, __HIP_MEMORY_SCOPE_AGENT) < target)
          __builtin_amdgcn_s_sleep(2);
        (void)__hip_atomic_load(counter, __ATOMIC_ACQUIRE, __HIP_MEMORY_SCOPE_AGENT);
      }
      __syncthreads();
    }
  }
#pragma unroll
  for (int a = 0; a < 2; ++a)
#pragma unroll
    for (int r = 0; r < 4; ++r) {
      const int b = (2 * wv + a) * 16 + lq * 4 + r;
      if (TRACK_C) cOut[b * H_ + j0 + lr] = mblend[a][r];
      else         mhOut[b * H_ + j0 + lr] = mblend[a][r];
    }
}

// ---------------------------------------------------------------------------
// head: logits = [mh, sim] @ fcW^T + fcb ; log_softmax
// ---------------------------------------------------------------------------
__global__ __launch_bounds__(128) void final_k(
    const float* __restrict__ mh, const float* __restrict__ sim,
    const float* __restrict__ fcW, const float* __restrict__ fcb,
    float* __restrict__ out)
{
  const int b = threadIdx.x;
  float l[3];
#pragma unroll
  for (int cc = 0; cc < 3; ++cc) {
    const float* wr = fcW + cc * (H_ + 1);
    float s = fcb[cc] + sim[b] * wr[H_];
    for (int j = 0; j < H_; ++j) s += mh[b * H_ + j] * wr[j];
    l[cc] = s;
  }
  const float m = fmaxf(l[0], fmaxf(l[1], l[2]));
  const float lse = m + logf(__expf(l[0] - m) + __expf(l[1] - m) + __expf(l[2] - m));
  out[b * 3 + 0] = l[0] - lse;
  out[b * 3 + 1] = l[1] - lse;
  out[b * 3 + 2] = l[2] - lse;
}

extern "C" void kernel_launch(void* const* d_in, const int* in_sizes, int n_in,
                              void* d_out, int out_size, void* d_ws, size_t ws_size,
                              hipStream_t stream) {
  const int*   prem = (const int*)d_in[0];
  const int*   hypo = (const int*)d_in[1];
  const float* sim  = (const float*)d_in[2];
  const float* emb  = (const float*)d_in[3];
  const float* WihP = (const float*)d_in[4];
  const float* WhhP = (const float*)d_in[5];
  const float* bihP = (const float*)d_in[6];
  const float* bhhP = (const float*)d_in[7];
  const float* WihH = (const float*)d_in[8];
  const float* WhhH = (const float*)d_in[9];
  const float* bihH = (const float*)d_in[10];
  const float* bhhH = (const float*)d_in[11];
  const float* fcW  = (const float*)d_in[12];
  const float* fcb  = (const float*)d_in[13];
  float* out = (float*)d_out;

  char* ws = (char*)d_ws;
  const size_t XG_BYTES = (size_t)B_ * T_ * G_ * 2;       // 104,857,600
  const size_t HB_OFF  = XG_BYTES;                        // 2 x 128 x 512 bf16
  const size_t CL_OFF  = HB_OFF + (size_t)2 * B_ * H_ * 2;
  const size_t MH_OFF  = CL_OFF + (size_t)B_ * H_ * 4;
  const size_t CNT_OFF = MH_OFF + (size_t)B_ * H_ * 4;
  const size_t NEED    = CNT_OFF + 256;
  if (ws_size < NEED) return;  // visible failure instead of OOB corruption

  u16*   xg    = (u16*)ws;
  u16*   hbuf  = (u16*)(ws + HB_OFF);
  float* cLast = (float*)(ws + CL_OFF);
  float* mh    = (float*)(ws + MH_OFF);
  int*   cnt   = (int*)(ws + CNT_OFF);

  hipMemsetAsync(cnt, 0, 8, stream);   // zero both barrier counters each call

  dim3 gG(400, 64);
  xg_gemm<<<gG, 256, 0, stream>>>(prem, emb, WihP, bihP, bhhP, xg);
  lstm_rec<1><<<32, 256, 0, stream>>>(prem, xg, WhhP, hbuf, nullptr, cLast, nullptr, cnt);
  xg_gemm<<<gG, 256, 0, stream>>>(hypo, emb, WihH, bihH, bhhH, xg);
  lstm_rec<0><<<32, 256, 0, stream>>>(hypo, xg, WhhH, hbuf, cLast, nullptr, mh, cnt + 1);
  final_k<<<1, 128, 0, stream>>>(mh, sim, fcW, fcb, out);
}

// Round 3
// 3901.995 us; speedup vs baseline: 2.0489x; 2.0489x over previous
//
#include <hip/hip_runtime.h>
#include <hip/hip_bf16.h>

#define B_ 128
#define T_ 200
#define H_ 512
#define G_ 2048   // 4*H
#define E_ 300

typedef unsigned short u16;
typedef unsigned int u32;

using f32x4 = __attribute__((ext_vector_type(4))) float;
using s16x8 = __attribute__((ext_vector_type(8))) short;

__device__ __forceinline__ u16 f2bf(float f) {
  u32 u = __builtin_bit_cast(u32, f);
  u32 r = (u + 0x7fffu + ((u >> 16) & 1u)) >> 16;   // RNE
  return (u16)r;
}
__device__ __forceinline__ float bf2f(u16 s) {
  return __builtin_bit_cast(float, (u32)s << 16);
}

// ---- device-coherent (IF$-level, L1/L2-bypass) memory ops -----------------
__device__ __forceinline__ s16x8 ld_h16_sc(const void* p) {
  s16x8 r;
  asm volatile("global_load_dwordx4 %0, %1, off sc0 sc1" : "=v"(r) : "v"(p));
  return r;
}
__device__ __forceinline__ void st_h_sc(void* p, u32 v) {   // low 16 bits
  asm volatile("global_store_short %0, %1, off sc0 sc1" :: "v"(p), "v"(v));
}
__device__ __forceinline__ u32 ld_flag_sc(const void* p) {
  u32 r;
  asm volatile("global_load_dword %0, %1, off sc0 sc1\n\ts_waitcnt vmcnt(0)"
               : "=v"(r) : "v"(p) : "memory");
  return r;
}
__device__ __forceinline__ void st_flag_sc(void* p, u32 v) {
  asm volatile("global_store_dword %0, %1, off sc0 sc1" :: "v"(p), "v"(v) : "memory");
}

// ---------------------------------------------------------------------------
// xg = emb[tok] @ Wih^T + bih + bhh   (unchanged, known-good)
// ---------------------------------------------------------------------------
__global__ __launch_bounds__(256) void xg_gemm(
    const int* __restrict__ tok, const float* __restrict__ emb,
    const float* __restrict__ Wih, const float* __restrict__ bih,
    const float* __restrict__ bhh, u16* __restrict__ xg)
{
  __shared__ u16 Al[64 * 320];
  __shared__ u16 Bl[32 * 320];
  __shared__ int tks[64];
  const int tid = threadIdx.x;
  const int m0 = blockIdx.x * 64;
  const int n0 = blockIdx.y * 32;
  if (tid < 64) tks[tid] = tok[m0 + tid];
  __syncthreads();
  {
    const int row = tid >> 2, part = tid & 3;
    const float* erow = emb + (size_t)tks[row] * E_;
    char* base = (char*)Al + row * 640;
    const int swz = (row & 7) << 4;
#pragma unroll
    for (int i = 0; i < 40; ++i) {
      const int kw = part * 40 + i;
      const int k = kw * 2;
      const float v0 = (k < E_) ? erow[k] : 0.f;
      const float v1 = (k + 1 < E_) ? erow[k + 1] : 0.f;
      *(u32*)(base + ((kw * 4) ^ swz)) = (u32)f2bf(v0) | ((u32)f2bf(v1) << 16);
    }
    const int brow = tid >> 3, bpart = tid & 7;
    const float* wrow = Wih + (size_t)(n0 + brow) * E_;
    char* bbase = (char*)Bl + brow * 640;
    const int bswz = (brow & 7) << 4;
#pragma unroll
    for (int i = 0; i < 20; ++i) {
      const int kw = bpart * 20 + i;
      const int k = kw * 2;
      const float v0 = (k < E_) ? wrow[k] : 0.f;
      const float v1 = (k + 1 < E_) ? wrow[k + 1] : 0.f;
      *(u32*)(bbase + ((kw * 4) ^ bswz)) = (u32)f2bf(v0) | ((u32)f2bf(v1) << 16);
    }
  }
  __syncthreads();
  const int wv = tid >> 6, ln = tid & 63, lr = ln & 15, lq = ln >> 4;
  f32x4 acc0 = {0.f, 0.f, 0.f, 0.f}, acc1 = {0.f, 0.f, 0.f, 0.f};
  const int arow = wv * 16 + lr;
  const char* abase = (const char*)Al + arow * 640;
  const int aswz = (arow & 7) << 4;
  const char* b0base = (const char*)Bl + lr * 640;
  const char* b1base = (const char*)Bl + (16 + lr) * 640;
  const int bswz2 = (lr & 7) << 4;
#pragma unroll
  for (int ks = 0; ks < 10; ++ks) {
    const int kb = ks * 64 + lq * 16;
    s16x8 af  = *(const s16x8*)(abase  + (kb ^ aswz));
    s16x8 bf0 = *(const s16x8*)(b0base + (kb ^ bswz2));
    s16x8 bf1 = *(const s16x8*)(b1base + (kb ^ bswz2));
    acc0 = __builtin_amdgcn_mfma_f32_16x16x32_bf16(af, bf0, acc0, 0, 0, 0);
    acc1 = __builtin_amdgcn_mfma_f32_16x16x32_bf16(af, bf1, acc1, 0, 0, 0);
  }
#pragma unroll
  for (int r = 0; r < 4; ++r) {
    const int m = m0 + wv * 16 + lq * 4 + r;
    const int gA = n0 + lr;
    const int gB = n0 + 16 + lr;
    xg[(size_t)m * G_ + gA] = f2bf(acc0[r] + bih[gA] + bhh[gA]);
    xg[(size_t)m * G_ + gB] = f2bf(acc1[r] + bih[gB] + bhh[gB]);
  }
}

// ---------------------------------------------------------------------------
// Persistent LSTM recurrence, v2.1 (v2 + A-fragment lq*8 offset fix).
// 64 WGs x 512 thr. WG = (grp, jt): batch group grp (64 rows), j-slice jt (16).
// 8 waves: wave = (bt = wv>>1 in 0..3, kh = wv&1 K-half). Whh B-frags live in
// VGPRs (bf16, loaded once). h exchanged via sc0sc1 (IF$-coherent) stores/loads
// with per-WG single-writer flags — no fences, no atomics, no L2 inval.
// ---------------------------------------------------------------------------
template<int TRACK_C>
__global__ __launch_bounds__(512, 2) void lstm_rec(
    const int* __restrict__ tok, const u16* __restrict__ xg,
    const float* __restrict__ Whh, u16* __restrict__ hbuf,
    const float* __restrict__ c0in, float* __restrict__ cOut,
    float* __restrict__ mhOut, u32* __restrict__ flags)
{
  __shared__ f32x4 red[4][4][64];   // 16 KB partial-sum exchange
  const int tid = threadIdx.x;
  const int wv = tid >> 6, ln = tid & 63, lr = ln & 15, lq = ln >> 4;
  const int bt = wv >> 1, kh = wv & 1;
  const int grp = (int)blockIdx.x >> 5, jt = (int)blockIdx.x & 31;
  const int j0 = jt * 16, bg0 = grp * 64;
  u32* gflags = flags + grp * 512;          // 32 flags x 16 u32 pad

  // ---- persistent B fragments: Bf[q][ks] = Whh[q*512+j0+lr][kh*256+ks*32+lq*8 ..+8]
  s16x8 Bf[4][8];
#pragma unroll
  for (int q = 0; q < 4; ++q) {
    const float* wr = Whh + (size_t)(q * H_ + j0 + lr) * H_ + kh * 256 + lq * 8;
#pragma unroll
    for (int ks = 0; ks < 8; ++ks) {
      const float* wp = wr + ks * 32;
      s16x8 f;
#pragma unroll
      for (int i = 0; i < 8; ++i) f[i] = (short)f2bf(wp[i]);
      Bf[q][ks] = f;
    }
  }

  float c[4], mb[4];
#pragma unroll
  for (int r = 0; r < 4; ++r) {
    const int b = bg0 + bt * 16 + lq * 4 + r;
    float cv = 0.f;
    if (!TRACK_C) cv = c0in[b * H_ + j0 + lr];
    c[r] = cv;
    mb[r] = TRACK_C ? cv : 0.f;
  }

  for (int t = 0; t < T_; ++t) {
    const u16* hrd = hbuf + (t & 1) * (B_ * H_);
    u16* hwr = hbuf + ((t + 1) & 1) * (B_ * H_);

    // prefetch xg + tok for this step (cached loads; hidden under the poll)
    float gx[4][4];
    int tk[4];
    if (kh == 0) {
#pragma unroll
      for (int r = 0; r < 4; ++r) {
        const int b = bg0 + bt * 16 + lq * 4 + r;
        tk[r] = tok[b * T_ + t];
        const size_t xo = ((size_t)b * T_ + t) * G_ + j0 + lr;
#pragma unroll
        for (int q = 0; q < 4; ++q) gx[q][r] = bf2f(xg[xo + q * H_]);
      }
    }

    // wait: all 32 producers of this group published h_t  (flag >= t)
    if (wv == 0 && t > 0) {
      const u32* pp = gflags + (ln & 31) * 16;
      int guard = 0;
      for (;;) {
        u32 v = ld_flag_sc(pp);
        if (__all((int)(v >= (u32)t))) break;
        if (++guard > (1 << 22)) break;     // bail out instead of hanging
        __builtin_amdgcn_s_sleep(2);
      }
    }
    __syncthreads();                         // barrier A
    __builtin_amdgcn_sched_barrier(0);

    // h_t loads (IF$-coherent), 8 x 16B per lane
    // A-frag layout for 16x16x32: row = lane&15, k = (lane>>4)*8 + i  (+32/ks)
    s16x8 ha[8];
    const u16* hb = hrd + (size_t)(bg0 + bt * 16 + lr) * H_ + kh * 256 + lq * 8;  // FIX: + lq*8
#pragma unroll
    for (int ks = 0; ks < 8; ++ks) ha[ks] = ld_h16_sc(hb + ks * 32);
    asm volatile("s_waitcnt vmcnt(0)" ::: "memory");
    __builtin_amdgcn_sched_barrier(0);

    f32x4 acc[4];
#pragma unroll
    for (int q = 0; q < 4; ++q) acc[q] = (f32x4){0.f, 0.f, 0.f, 0.f};
#pragma unroll
    for (int ks = 0; ks < 8; ++ks)
#pragma unroll
      for (int q = 0; q < 4; ++q)
        acc[q] = __builtin_amdgcn_mfma_f32_16x16x32_bf16(ha[ks], Bf[q][ks], acc[q], 0, 0, 0);

    if (kh == 1) {
#pragma unroll
      for (int q = 0; q < 4; ++q) red[bt][q][ln] = acc[q];
    }
    __syncthreads();                         // barrier B
    if (kh == 0) {
#pragma unroll
      for (int q = 0; q < 4; ++q) acc[q] += red[bt][q][ln];
#pragma unroll
      for (int r = 0; r < 4; ++r) {
        const int b = bg0 + bt * 16 + lq * 4 + r;
        const float gi = acc[0][r] + gx[0][r];
        const float gf = acc[1][r] + gx[1][r];
        const float gg = acc[2][r] + gx[2][r];
        const float go = acc[3][r] + gx[3][r];
        const float si = 1.f / (1.f + __expf(-gi));
        const float sf = 1.f / (1.f + __expf(-gf));
        const float so = 1.f / (1.f + __expf(-go));
        const float tg = 2.f / (1.f + __expf(-2.f * gg)) - 1.f;
        const float cn = sf * c[r] + si * tg;
        const float tc = 2.f / (1.f + __expf(-2.f * cn)) - 1.f;
        const float hn = so * tc;
        c[r] = cn;
        if (tk[r] != 0) mb[r] = TRACK_C ? cn : hn;
        st_h_sc(hwr + (size_t)b * H_ + j0 + lr, (u32)f2bf(hn));
      }
      asm volatile("s_waitcnt vmcnt(0)" ::: "memory");   // drain sc1 stores
    }
    __syncthreads();                         // barrier C
    if (tid == 0 && t + 1 < T_) st_flag_sc(gflags + jt * 16, (u32)(t + 1));
  }

  if (kh == 0) {
#pragma unroll
    for (int r = 0; r < 4; ++r) {
      const int b = bg0 + bt * 16 + lq * 4 + r;
      if (TRACK_C) cOut[b * H_ + j0 + lr] = mb[r];
      else         mhOut[b * H_ + j0 + lr] = mb[r];
    }
  }
}

// ---------------------------------------------------------------------------
// head: logits = [mh, sim] @ fcW^T + fcb ; log_softmax
// ---------------------------------------------------------------------------
__global__ __launch_bounds__(128) void final_k(
    const float* __restrict__ mh, const float* __restrict__ sim,
    const float* __restrict__ fcW, const float* __restrict__ fcb,
    float* __restrict__ out)
{
  const int b = threadIdx.x;
  float l[3];
#pragma unroll
  for (int cc = 0; cc < 3; ++cc) {
    const float* wr = fcW + cc * (H_ + 1);
    float s = fcb[cc] + sim[b] * wr[H_];
    for (int j = 0; j < H_; ++j) s += mh[b * H_ + j] * wr[j];
    l[cc] = s;
  }
  const float m = fmaxf(l[0], fmaxf(l[1], l[2]));
  const float lse = m + logf(__expf(l[0] - m) + __expf(l[1] - m) + __expf(l[2] - m));
  out[b * 3 + 0] = l[0] - lse;
  out[b * 3 + 1] = l[1] - lse;
  out[b * 3 + 2] = l[2] - lse;
}

extern "C" void kernel_launch(void* const* d_in, const int* in_sizes, int n_in,
                              void* d_out, int out_size, void* d_ws, size_t ws_size,
                              hipStream_t stream) {
  const int*   prem = (const int*)d_in[0];
  const int*   hypo = (const int*)d_in[1];
  const float* sim  = (const float*)d_in[2];
  const float* emb  = (const float*)d_in[3];
  const float* WihP = (const float*)d_in[4];
  const float* WhhP = (const float*)d_in[5];
  const float* bihP = (const float*)d_in[6];
  const float* bhhP = (const float*)d_in[7];
  const float* WihH = (const float*)d_in[8];
  const float* WhhH = (const float*)d_in[9];
  const float* bihH = (const float*)d_in[10];
  const float* bhhH = (const float*)d_in[11];
  const float* fcW  = (const float*)d_in[12];
  const float* fcb  = (const float*)d_in[13];
  float* out = (float*)d_out;

  char* ws = (char*)d_ws;
  const size_t XG_BYTES = (size_t)B_ * T_ * G_ * 2;       // 104,857,600
  const size_t HB_OFF = XG_BYTES;                         // 2 x 128 x 512 bf16
  const size_t CL_OFF = HB_OFF + (size_t)2 * B_ * H_ * 2;
  const size_t MH_OFF = CL_OFF + (size_t)B_ * H_ * 4;
  const size_t FL_OFF = MH_OFF + (size_t)B_ * H_ * 4;
  const size_t NEED   = FL_OFF + 8192;
  if (ws_size < NEED) return;  // visible failure instead of OOB corruption

  u16*   xg    = (u16*)ws;
  u16*   hbuf  = (u16*)(ws + HB_OFF);
  float* cLast = (float*)(ws + CL_OFF);
  float* mh    = (float*)(ws + MH_OFF);
  u32*   flagsP = (u32*)(ws + FL_OFF);        // 4 KB
  u32*   flagsH = flagsP + 1024;              // 4 KB

  hipMemsetAsync(ws + FL_OFF, 0, 8192, stream);           // both flag regions

  dim3 gG(400, 64);
  xg_gemm<<<gG, 256, 0, stream>>>(prem, emb, WihP, bihP, bhhP, xg);
  hipMemsetAsync(hbuf, 0, (size_t)B_ * H_ * 2, stream);   // h0 = 0 (buffer 0)
  lstm_rec<1><<<64, 512, 0, stream>>>(prem, xg, WhhP, hbuf, nullptr, cLast, nullptr, flagsP);
  xg_gemm<<<gG, 256, 0, stream>>>(hypo, emb, WihH, bihH, bhhH, xg);
  hipMemsetAsync(hbuf, 0, (size_t)B_ * H_ * 2, stream);   // h0 = 0 (buffer 0)
  lstm_rec<0><<<64, 512, 0, stream>>>(hypo, xg, WhhH, hbuf, cLast, nullptr, mh, flagsH);
  final_k<<<1, 128, 0, stream>>>(mh, sim, fcW, fcb, out);
}

// Round 4
// 3126.662 us; speedup vs baseline: 2.5570x; 1.2480x over previous
//
#include <hip/hip_runtime.h>
#include <hip/hip_bf16.h>

#define B_ 128
#define T_ 200
#define H_ 512
#define G_ 2048   // 4*H
#define E_ 300

typedef unsigned short u16;
typedef unsigned int u32;

using f32x4 = __attribute__((ext_vector_type(4))) float;
using s16x8 = __attribute__((ext_vector_type(8))) short;

__device__ __forceinline__ u16 f2bf(float f) {
  u32 u = __builtin_bit_cast(u32, f);
  u32 r = (u + 0x7fffu + ((u >> 16) & 1u)) >> 16;   // RNE
  return (u16)r;
}
__device__ __forceinline__ float bf2f(u16 s) {
  return __builtin_bit_cast(float, (u32)s << 16);
}

// ---- device-coherent (L1/L2-bypass) memory ops ----------------------------
__device__ __forceinline__ s16x8 ld_h16_sc(const void* p) {
  s16x8 r;
  asm volatile("global_load_dwordx4 %0, %1, off sc0 sc1" : "=v"(r) : "v"(p));
  return r;
}
__device__ __forceinline__ void st_h_sc(void* p, u32 v) {   // low 16 bits
  asm volatile("global_store_short %0, %1, off sc0 sc1" :: "v"(p), "v"(v));
}
__device__ __forceinline__ void ld_flag2_sc(const u32* p0, const u32* p1,
                                            u32& a, u32& b) {
  asm volatile("global_load_dword %0, %2, off sc0 sc1\n\t"
               "global_load_dword %1, %3, off sc0 sc1\n\t"
               "s_waitcnt vmcnt(0)"
               : "=&v"(a), "=&v"(b) : "v"(p0), "v"(p1) : "memory");
}
__device__ __forceinline__ void st_flag_sc(void* p, u32 v) {
  asm volatile("global_store_dword %0, %1, off sc0 sc1" :: "v"(p), "v"(v) : "memory");
}

// ---------------------------------------------------------------------------
// Wih (4H x E f32) -> bf16 padded [4H x 320]
// ---------------------------------------------------------------------------
__global__ __launch_bounds__(256) void wih_cvt(
    const float* __restrict__ W, u16* __restrict__ Wb)
{
  const int idx = blockIdx.x * 256 + threadIdx.x;   // 2048*320 total
  const int row = idx / 320, k = idx - row * 320;
  const float v = (k < E_) ? W[row * E_ + k] : 0.f;
  Wb[idx] = f2bf(v);
}

// ---------------------------------------------------------------------------
// xg = emb[tok] @ Wih^T + bih + bhh, v2: tile 64(M) x 256(N), N-loop inside.
// A staged once per block (gather+cvt amortized 8x vs r1's 64 restages);
// B staged from pre-converted bf16 Wb as pure 16B copies.
// grid (400, 8), block 256.
// ---------------------------------------------------------------------------
__global__ __launch_bounds__(256) void xg_gemm(
    const int* __restrict__ tok, const float* __restrict__ emb,
    const u16* __restrict__ Wb, const float* __restrict__ bih,
    const float* __restrict__ bhh, u16* __restrict__ xg)
{
  __shared__ u16 Al[64 * 320];
  __shared__ u16 Bl[32 * 320];
  __shared__ int tks[64];
  const int tid = threadIdx.x;
  const int m0 = blockIdx.x * 64;
  if (tid < 64) tks[tid] = tok[m0 + tid];
  __syncthreads();
  {
    const int row = tid >> 2, part = tid & 3;
    const float* erow = emb + (size_t)tks[row] * E_;
    char* base = (char*)Al + row * 640;
    const int swz = (row & 7) << 4;
#pragma unroll
    for (int i = 0; i < 40; ++i) {
      const int kw = part * 40 + i;
      const int k = kw * 2;
      const float v0 = (k < E_) ? erow[k] : 0.f;
      const float v1 = (k + 1 < E_) ? erow[k + 1] : 0.f;
      *(u32*)(base + ((kw * 4) ^ swz)) = (u32)f2bf(v0) | ((u32)f2bf(v1) << 16);
    }
  }
  __syncthreads();
  const int wv = tid >> 6, ln = tid & 63, lr = ln & 15, lq = ln >> 4;
  const int arow = wv * 16 + lr;
  const char* abase = (const char*)Al + arow * 640;
  const int aswz = (arow & 7) << 4;
  const int brow = tid >> 3, bpart = tid & 7;
  char* bdst = (char*)Bl + brow * 640;
  const int bswz = (brow & 7) << 4;
  const char* b0base = (const char*)Bl + lr * 640;
  const char* b1base = (const char*)Bl + (16 + lr) * 640;
  const int bswz2 = (lr & 7) << 4;

  for (int ni = 0; ni < 8; ++ni) {
    const int n0 = blockIdx.y * 256 + ni * 32;
    {
      const u16* src = Wb + (size_t)(n0 + brow) * 320 + bpart * 40;
#pragma unroll
      for (int i = 0; i < 5; ++i) {
        s16x8 v = *(const s16x8*)(src + i * 8);
        *(s16x8*)(bdst + (((bpart * 5 + i) * 16) ^ bswz)) = v;
      }
    }
    __syncthreads();
    f32x4 acc0 = {0.f, 0.f, 0.f, 0.f}, acc1 = {0.f, 0.f, 0.f, 0.f};
#pragma unroll
    for (int ks = 0; ks < 10; ++ks) {
      const int kb = ks * 64 + lq * 16;
      s16x8 af  = *(const s16x8*)(abase  + (kb ^ aswz));
      s16x8 bf0 = *(const s16x8*)(b0base + (kb ^ bswz2));
      s16x8 bf1 = *(const s16x8*)(b1base + (kb ^ bswz2));
      acc0 = __builtin_amdgcn_mfma_f32_16x16x32_bf16(af, bf0, acc0, 0, 0, 0);
      acc1 = __builtin_amdgcn_mfma_f32_16x16x32_bf16(af, bf1, acc1, 0, 0, 0);
    }
#pragma unroll
    for (int r = 0; r < 4; ++r) {
      const int m = m0 + wv * 16 + lq * 4 + r;
      const int gA = n0 + lr;
      const int gB = n0 + 16 + lr;
      xg[(size_t)m * G_ + gA] = f2bf(acc0[r] + bih[gA] + bhh[gA]);
      xg[(size_t)m * G_ + gB] = f2bf(acc1[r] + bih[gB] + bhh[gB]);
    }
    __syncthreads();
  }
}

// ---------------------------------------------------------------------------
// Persistent LSTM recurrence, v3: one __syncthreads per step.
// 64 WGs x 512 thr. WG = (grp, jt). 8 waves = (bt 0..3) x (kh 0..1).
// Whh B-frags in VGPRs. Per-(jt,bt) flags (128/group, 64B padded), published
// by each kh0 wave after its own store drain; ALL waves poll independently.
// Reuse safety: kh1's next red-write / buffer overwrite are ordered behind
// its own WG's kh0 flag (set after kh0 read red and finished stores).
// ---------------------------------------------------------------------------
template<int TRACK_C>
__global__ __launch_bounds__(512, 2) void lstm_rec(
    const int* __restrict__ tok, const u16* __restrict__ xg,
    const float* __restrict__ Whh, u16* __restrict__ hbuf,
    const float* __restrict__ c0in, float* __restrict__ cOut,
    float* __restrict__ mhOut, u32* __restrict__ flags)
{
  __shared__ f32x4 red[4][4][64];   // 16 KB partial-sum exchange
  const int tid = threadIdx.x;
  const int wv = tid >> 6, ln = tid & 63, lr = ln & 15, lq = ln >> 4;
  const int bt = wv >> 1, kh = wv & 1;
  const int grp = (int)blockIdx.x >> 5, jt = (int)blockIdx.x & 31;
  const int j0 = jt * 16, bg0 = grp * 64;
  u32* gflags = flags + grp * 2048;          // 128 flags x 16 u32 pad

  // persistent B fragments: Bf[q][ks] = Whh[q*512+j0+lr][kh*256+ks*32+lq*8 ..+8]
  s16x8 Bf[4][8];
#pragma unroll
  for (int q = 0; q < 4; ++q) {
    const float* wr = Whh + (size_t)(q * H_ + j0 + lr) * H_ + kh * 256 + lq * 8;
#pragma unroll
    for (int ks = 0; ks < 8; ++ks) {
      const float* wp = wr + ks * 32;
      s16x8 f;
#pragma unroll
      for (int i = 0; i < 8; ++i) f[i] = (short)f2bf(wp[i]);
      Bf[q][ks] = f;
    }
  }

  float c[4], mb[4];
#pragma unroll
  for (int r = 0; r < 4; ++r) {
    const int b = bg0 + bt * 16 + lq * 4 + r;
    float cv = 0.f;
    if (!TRACK_C) cv = c0in[b * H_ + j0 + lr];
    c[r] = cv;
    mb[r] = TRACK_C ? cv : 0.f;
  }

  const u32* p0 = gflags + ln * 16;          // flags 0..63
  const u32* p1 = gflags + (64 + ln) * 16;   // flags 64..127

  for (int t = 0; t < T_; ++t) {
    const u16* hrd = hbuf + (t & 1) * (B_ * H_);
    u16* hwr = hbuf + ((t + 1) & 1) * (B_ * H_);

    // prefetch xg + tok for this step (cached; latency hides under the poll)
    float gx[4][4];
    int tk[4];
    if (kh == 0) {
#pragma unroll
      for (int r = 0; r < 4; ++r) {
        const int b = bg0 + bt * 16 + lq * 4 + r;
        tk[r] = tok[b * T_ + t];
        const size_t xo = ((size_t)b * T_ + t) * G_ + j0 + lr;
#pragma unroll
        for (int q = 0; q < 4; ++q) gx[q][r] = bf2f(xg[xo + q * H_]);
      }
    }

    // every wave polls: all 128 producer flags of this group must reach t
    if (t > 0) {
      int guard = 0;
      u32 a, b;
      for (;;) {
        ld_flag2_sc(p0, p1, a, b);
        if (__all((int)(a >= (u32)t && b >= (u32)t))) break;
        if (++guard > (1 << 20)) break;     // bail out instead of hanging
        __builtin_amdgcn_s_sleep(2);
      }
    }
    __builtin_amdgcn_sched_barrier(0);

    // h_t loads (coherent), A-frag: row = lane&15, k = (lane>>4)*8 + i (+32/ks)
    s16x8 ha[8];
    const u16* hb = hrd + (size_t)(bg0 + bt * 16 + lr) * H_ + kh * 256 + lq * 8;
#pragma unroll
    for (int ks = 0; ks < 8; ++ks) ha[ks] = ld_h16_sc(hb + ks * 32);
    asm volatile("s_waitcnt vmcnt(0)" ::: "memory");
    __builtin_amdgcn_sched_barrier(0);

    f32x4 acc[4];
#pragma unroll
    for (int q = 0; q < 4; ++q) acc[q] = (f32x4){0.f, 0.f, 0.f, 0.f};
#pragma unroll
    for (int ks = 0; ks < 8; ++ks)
#pragma unroll
      for (int q = 0; q < 4; ++q)
        acc[q] = __builtin_amdgcn_mfma_f32_16x16x32_bf16(ha[ks], Bf[q][ks], acc[q], 0, 0, 0);

    if (kh == 1) {
#pragma unroll
      for (int q = 0; q < 4; ++q) red[bt][q][ln] = acc[q];
    }
    __syncthreads();                         // the one barrier: red ready
    if (kh == 0) {
#pragma unroll
      for (int q = 0; q < 4; ++q) acc[q] += red[bt][q][ln];
      const bool last = (t == T_ - 1);
#pragma unroll
      for (int r = 0; r < 4; ++r) {
        const int b = bg0 + bt * 16 + lq * 4 + r;
        const float gi = acc[0][r] + gx[0][r];
        const float gf = acc[1][r] + gx[1][r];
        const float gg = acc[2][r] + gx[2][r];
        const float go = acc[3][r] + gx[3][r];
        const float si = 1.f / (1.f + __expf(-gi));
        const float sf = 1.f / (1.f + __expf(-gf));
        const float so = 1.f / (1.f + __expf(-go));
        const float tg = 2.f / (1.f + __expf(-2.f * gg)) - 1.f;
        const float cn = sf * c[r] + si * tg;
        const float tc = 2.f / (1.f + __expf(-2.f * cn)) - 1.f;
        const float hn = so * tc;
        c[r] = cn;
        if (tk[r] != 0) mb[r] = TRACK_C ? cn : hn;
        if (!last) st_h_sc(hwr + (size_t)b * H_ + j0 + lr, (u32)f2bf(hn));
      }
      asm volatile("s_waitcnt vmcnt(0)" ::: "memory");   // drain h stores
      if (ln == 0 && t + 1 < T_)
        st_flag_sc(gflags + (jt * 4 + bt) * 16, (u32)(t + 1));
    }
  }

  if (kh == 0) {
#pragma unroll
    for (int r = 0; r < 4; ++r) {
      const int b = bg0 + bt * 16 + lq * 4 + r;
      if (TRACK_C) cOut[b * H_ + j0 + lr] = mb[r];
      else         mhOut[b * H_ + j0 + lr] = mb[r];
    }
  }
}

// ---------------------------------------------------------------------------
// head: logits = [mh, sim] @ fcW^T + fcb ; log_softmax
// ---------------------------------------------------------------------------
__global__ __launch_bounds__(128) void final_k(
    const float* __restrict__ mh, const float* __restrict__ sim,
    const float* __restrict__ fcW, const float* __restrict__ fcb,
    float* __restrict__ out)
{
  const int b = threadIdx.x;
  float l[3];
#pragma unroll
  for (int cc = 0; cc < 3; ++cc) {
    const float* wr = fcW + cc * (H_ + 1);
    float s = fcb[cc] + sim[b] * wr[H_];
    for (int j = 0; j < H_; ++j) s += mh[b * H_ + j] * wr[j];
    l[cc] = s;
  }
  const float m = fmaxf(l[0], fmaxf(l[1], l[2]));
  const float lse = m + logf(__expf(l[0] - m) + __expf(l[1] - m) + __expf(l[2] - m));
  out[b * 3 + 0] = l[0] - lse;
  out[b * 3 + 1] = l[1] - lse;
  out[b * 3 + 2] = l[2] - lse;
}

extern "C" void kernel_launch(void* const* d_in, const int* in_sizes, int n_in,
                              void* d_out, int out_size, void* d_ws, size_t ws_size,
                              hipStream_t stream) {
  const int*   prem = (const int*)d_in[0];
  const int*   hypo = (const int*)d_in[1];
  const float* sim  = (const float*)d_in[2];
  const float* emb  = (const float*)d_in[3];
  const float* WihP = (const float*)d_in[4];
  const float* WhhP = (const float*)d_in[5];
  const float* bihP = (const float*)d_in[6];
  const float* bhhP = (const float*)d_in[7];
  const float* WihH = (const float*)d_in[8];
  const float* WhhH = (const float*)d_in[9];
  const float* bihH = (const float*)d_in[10];
  const float* bhhH = (const float*)d_in[11];
  const float* fcW  = (const float*)d_in[12];
  const float* fcb  = (const float*)d_in[13];
  float* out = (float*)d_out;

  char* ws = (char*)d_ws;
  const size_t XG_BYTES = (size_t)B_ * T_ * G_ * 2;       // 104,857,600
  const size_t HB_OFF = XG_BYTES;                         // 2 x 128 x 512 bf16
  const size_t CL_OFF = HB_OFF + (size_t)2 * B_ * H_ * 2;
  const size_t MH_OFF = CL_OFF + (size_t)B_ * H_ * 4;
  const size_t FL_OFF = MH_OFF + (size_t)B_ * H_ * 4;     // 2 kernels x 16 KB
  const size_t WB_OFF = FL_OFF + 32768;
  const size_t NEED   = WB_OFF + (size_t)G_ * 320 * 2;    // +1.31 MB
  if (ws_size < NEED) return;  // visible failure instead of OOB corruption

  u16*   xg    = (u16*)ws;
  u16*   hbuf  = (u16*)(ws + HB_OFF);
  float* cLast = (float*)(ws + CL_OFF);
  float* mh    = (float*)(ws + MH_OFF);
  u32*   flagsP = (u32*)(ws + FL_OFF);        // 16 KB (2 grp x 128 x 64B)
  u32*   flagsH = flagsP + 4096;              // 16 KB
  u16*   Wb    = (u16*)(ws + WB_OFF);

  hipMemsetAsync(ws + FL_OFF, 0, 32768, stream);          // both flag regions

  dim3 gG(400, 8);
  wih_cvt<<<2560, 256, 0, stream>>>(WihP, Wb);
  xg_gemm<<<gG, 256, 0, stream>>>(prem, emb, Wb, bihP, bhhP, xg);
  hipMemsetAsync(hbuf, 0, (size_t)B_ * H_ * 2, stream);   // h0 = 0 (buffer 0)
  lstm_rec<1><<<64, 512, 0, stream>>>(prem, xg, WhhP, hbuf, nullptr, cLast, nullptr, flagsP);
  wih_cvt<<<2560, 256, 0, stream>>>(WihH, Wb);            // stream-ordered reuse
  xg_gemm<<<gG, 256, 0, stream>>>(hypo, emb, Wb, bihH, bhhH, xg);
  hipMemsetAsync(hbuf, 0, (size_t)B_ * H_ * 2, stream);   // h0 = 0 (buffer 0)
  lstm_rec<0><<<64, 512, 0, stream>>>(hypo, xg, WhhH, hbuf, cLast, nullptr, mh, flagsH);
  final_k<<<1, 128, 0, stream>>>(mh, sim, fcW, fcb, out);
}